// Round 14
// baseline (2346.620 us; speedup 1.0000x reference)
//
#include <hip/hip_runtime.h>
#include <hip/hip_fp16.h>
#include <math.h>

#define B_ 64
#define T_ 512

typedef _Float16 h2_t __attribute__((ext_vector_type(2)));
typedef _Float16 f16x8 __attribute__((ext_vector_type(8)));
typedef float f32x4 __attribute__((ext_vector_type(4)));

__device__ __forceinline__ float fdot2u(unsigned int a, unsigned int b, float c) {
#if __has_builtin(__builtin_amdgcn_fdot2)
    return __builtin_amdgcn_fdot2(__builtin_bit_cast(h2_t, a),
                                  __builtin_bit_cast(h2_t, b), c, false);
#else
    const __half2 ah = __builtin_bit_cast(__half2, a);
    const __half2 bh = __builtin_bit_cast(__half2, b);
    const float2 af = __half22float2(ah), bf = __half22float2(bh);
    return c + af.x * bf.x + af.y * bf.y;
#endif
}
__device__ __forceinline__ unsigned int pack_h2(float x, float y) {
    const __half2 h = __float22half2_rn(make_float2(x, y));
    return __builtin_bit_cast(unsigned int, h);
}
__device__ __forceinline__ float ubits(unsigned int a) { return __builtin_bit_cast(float, a); }
__device__ __forceinline__ unsigned short f2h_bits(float x) {
    return __builtin_bit_cast(unsigned short, (_Float16)x);
}
__device__ __forceinline__ float h2f_bits(unsigned int bits) {
    return (float)__builtin_bit_cast(_Float16, (unsigned short)(bits & 0xffffu));
}

__device__ __forceinline__ float fsig(float z) { return 1.f / (1.f + __expf(-z)); }
__device__ __forceinline__ float ftanh(float z) {
    const float e = __expf(2.f * z);
    return 1.f - 2.f / (e + 1.f);
}

// LDS-only barrier: lgkmcnt(0) + s_barrier, no vmcnt drain (v12-proven).
__device__ __forceinline__ void bar_lds() {
    asm volatile("s_waitcnt lgkmcnt(0)" ::: "memory");
    __builtin_amdgcn_s_barrier();
    asm volatile("" ::: "memory");
}

// ---------------------------------------------------------------------------
// GEMM v3 (MFMA, r13-verified: ~30us/dispatch): C = (A*mask)@W + bias.
// 128x128 tile, 4 waves (64x64 quadrant), K-step 32, mfma_f32_16x16x32_f16.
// UNCHANGED from r13.
// ---------------------------------------------------------------------------
__global__ __launch_bounds__(256) void gemm_mask_mfma(
    const float* __restrict__ A, const float* __restrict__ W,
    const float* __restrict__ bias, const float* __restrict__ mask,
    float* __restrict__ C, int M, int N, int K)
{
    __shared__ __align__(16) unsigned int AsT[128][20];
    __shared__ __align__(16) unsigned int BsT[128][20];

    const int tid = threadIdx.x;
    const int bn = blockIdx.x;          // N/128
    const int bm = blockIdx.y;          // M/128
    const int row0 = bm * 128;
    const int col0 = bn * 128;
    const int b = row0 / T_;            // 128-row tile stays inside one batch elem

    const int wave = tid >> 6;
    const int lane = tid & 63;
    const int wm = (wave >> 1) * 64;    // wave quadrant row offset
    const int wn = (wave & 1) * 64;     // wave quadrant col offset
    const int lr = lane & 15;           // fragment row/col
    const int g  = lane >> 4;           // k-group 0..3

    f32x4 acc[4][4];
#pragma unroll
    for (int i = 0; i < 4; ++i)
#pragma unroll
        for (int j = 0; j < 4; ++j) acc[i][j] = (f32x4){0.f, 0.f, 0.f, 0.f};

    for (int kk = 0; kk < K; kk += 32) {
        // ---- stage A*mask: thread (m = tid>>1, half = tid&1 -> 16 k) ----
        {
            const int m = tid >> 1;
            const int half = tid & 1;
            const float* ap = A + (size_t)(row0 + m) * K + kk + half * 16;
            const float* mp = mask + (size_t)b * K + kk + half * 16;
            const float4 a0 = *(const float4*)(ap);
            const float4 a1 = *(const float4*)(ap + 4);
            const float4 a2 = *(const float4*)(ap + 8);
            const float4 a3 = *(const float4*)(ap + 12);
            const float4 m0 = *(const float4*)(mp);
            const float4 m1 = *(const float4*)(mp + 4);
            const float4 m2 = *(const float4*)(mp + 8);
            const float4 m3 = *(const float4*)(mp + 12);
            uint4 lo, hi;
            lo.x = pack_h2(a0.x * m0.x, a0.y * m0.y);
            lo.y = pack_h2(a0.z * m0.z, a0.w * m0.w);
            lo.z = pack_h2(a1.x * m1.x, a1.y * m1.y);
            lo.w = pack_h2(a1.z * m1.z, a1.w * m1.w);
            hi.x = pack_h2(a2.x * m2.x, a2.y * m2.y);
            hi.y = pack_h2(a2.z * m2.z, a2.w * m2.w);
            hi.z = pack_h2(a3.x * m3.x, a3.y * m3.y);
            hi.w = pack_h2(a3.z * m3.z, a3.w * m3.w);
            *(uint4*)&AsT[m][half * 8 + 0] = lo;   // 80B row stride: 16B-aligned
            *(uint4*)&AsT[m][half * 8 + 4] = hi;
        }
        // ---- stage B (W k-pair transposed) ----
        {
            const int kp = tid >> 4;
            const int t15 = tid & 15;
            const float* w0p = W + (size_t)(kk + 2 * kp) * N + col0 + t15;
            const float* w1p = W + (size_t)(kk + 2 * kp + 1) * N + col0 + t15;
#pragma unroll
            for (int i = 0; i < 8; ++i) {
                const int n = t15 + 16 * i;
                BsT[n][kp] = pack_h2(w0p[16 * i], w1p[16 * i]);
            }
        }
        __syncthreads();

        // ---- fragments + 16 MFMA per wave ----
        f16x8 af[4], bf[4];
#pragma unroll
        for (int i = 0; i < 4; ++i)
            af[i] = __builtin_bit_cast(f16x8, *(const uint4*)&AsT[wm + 16 * i + lr][g * 4]);
#pragma unroll
        for (int j = 0; j < 4; ++j)
            bf[j] = __builtin_bit_cast(f16x8, *(const uint4*)&BsT[wn + 16 * j + lr][g * 4]);
#pragma unroll
        for (int i = 0; i < 4; ++i)
#pragma unroll
            for (int j = 0; j < 4; ++j)
                acc[i][j] = __builtin_amdgcn_mfma_f32_16x16x32_f16(af[i], bf[j], acc[i][j], 0, 0, 0);
        __syncthreads();
    }

    // ---- epilogue: C/D mapping col = lane&15, row = (lane>>4)*4 + reg ----
#pragma unroll
    for (int j = 0; j < 4; ++j) {
        const int c = col0 + wn + 16 * j + lr;
        const float bv = bias[c];
#pragma unroll
        for (int i = 0; i < 4; ++i) {
            const int r0 = row0 + wm + 16 * i + g * 4;
            C[(size_t)(r0 + 0) * N + c] = acc[i][j][0] + bv;
            C[(size_t)(r0 + 1) * N + c] = acc[i][j][1] + bv;
            C[(size_t)(r0 + 2) * N + c] = acc[i][j][2] + bv;
            C[(size_t)(r0 + 3) * N + c] = acc[i][j][3] + bv;
        }
    }
}

// ---------------------------------------------------------------------------
// LSTM recurrence v21 = v16 (r9/r12 best, ~698us) + cell-phase ordering:
//  (1) publish atomic issued FIRST (it gates sibling polls; hout store was
//      occupying the VMEM slot ahead of it), then LDS own-quarter write,
//      then hout;
//  (2) xz prefetch issued BEFORE the zpS reduce (L2 latency hides under it);
//  (3) s_setprio(1) around the cell critical section (role diversity vs
//      poll/dot waves -> T5 precondition holds).
// Structure/protocol identical to v16. Lessons encoded: INLINE bodies (r8);
// 4-way split optimal (r10); broadcast b128 hW reads optimal (r11).
// ---------------------------------------------------------------------------
template <int HN, bool F16>
__global__ __launch_bounds__(1024, 4) void lstm_rec_v21(
    const float* __restrict__ xz,       // [B, T, 4*HN]
    const float* __restrict__ U,        // [HN, 4*HN]
    float* __restrict__ hout,           // [B, T, HN] or nullptr
    float* __restrict__ out_last,       // [B, HN] or nullptr
    unsigned int* __restrict__ hbuf)    // [2][B_*HN] tagged words
{
    constexpr int GATES = 4 * HN;
    constexpr int COLS = HN;
    constexpr int CP = COLS / 2;
    constexpr int NKG = 1024 / CP;
    constexpr int KH = HN / NKG;
    constexpr int HB = HN / 4;
    constexpr int KWORDS = F16 ? HN / 2 : HN;
    constexpr int WPT = F16 ? KH / 2 : KH;
    constexpr int COLSP = COLS + 2;
    constexpr int NR = 3 * HB / 2;

    __shared__ __align__(16) unsigned int hW[KWORDS];
    __shared__ __align__(16) float zpS[NKG * COLSP];

    const int tid = threadIdx.x;
    const int q = blockIdx.x >> 6;      // quarter 0..3
    const int b = blockIdx.x & 63;      // batch element (siblings 64 apart -> same XCD)

    const int cp = tid % CP;
    const int kq = tid / CP;            // wave-uniform (CP % 64 == 0)
    const int c0 = 2 * cp;
    const int group = c0 / HB;
    const int gcol = group * HN + q * HB + (c0 % HB);
    const int wbase = kq * WPT;

    // ---- one-time: load this thread's U slice into REGISTERS, then PIN ----
    uint2 ur[WPT];
#pragma unroll
    for (int j = 0; j < WPT; ++j) {
        const int w = wbase + j;
        if constexpr (F16) {
            const float2 r0 = *(const float2*)(U + (size_t)(2 * w) * GATES + gcol);
            const float2 r1 = *(const float2*)(U + (size_t)(2 * w + 1) * GATES + gcol);
            ur[j].x = pack_h2(r0.x, r1.x);
            ur[j].y = pack_h2(r0.y, r1.y);
        } else {
            const float2 r0 = *(const float2*)(U + (size_t)w * GATES + gcol);
            ur[j].x = __builtin_bit_cast(unsigned int, r0.x);
            ur[j].y = __builtin_bit_cast(unsigned int, r0.y);
        }
    }
#pragma unroll
    for (int j = 0; j < WPT; ++j)
        asm volatile("" : "+v"(ur[j].x), "+v"(ur[j].y));

    if (tid < KWORDS) hW[tid] = 0u;     // h_0 = 0
    float cst = 0.f;

    const float* xzcell = xz + (size_t)b * T_ * GATES + q * HB + tid;
    float z4[4] = {0.f, 0.f, 0.f, 0.f};
    if (tid < HB) {
#pragma unroll
        for (int g = 0; g < 4; ++g) z4[g] = xzcell[(size_t)g * HN];   // t=0
    }
    __syncthreads();   // one-time init barrier

#pragma unroll 1
    for (int t = 0; t < T_; ++t) {
        // ---- phase A: dot (U in regs, h from LDS) ----
        float acc0 = 0.f, acc1 = 0.f;
#pragma unroll
        for (int j = 0; j < WPT; j += 4) {
            const int w = wbase + j;
            const uint4 hw4 = *(const uint4*)&hW[w];    // wave-uniform broadcast
            if constexpr (F16) {
                acc0 = fdot2u(ur[j + 0].x, hw4.x, acc0); acc1 = fdot2u(ur[j + 0].y, hw4.x, acc1);
                acc0 = fdot2u(ur[j + 1].x, hw4.y, acc0); acc1 = fdot2u(ur[j + 1].y, hw4.y, acc1);
                acc0 = fdot2u(ur[j + 2].x, hw4.z, acc0); acc1 = fdot2u(ur[j + 2].y, hw4.z, acc1);
                acc0 = fdot2u(ur[j + 3].x, hw4.w, acc0); acc1 = fdot2u(ur[j + 3].y, hw4.w, acc1);
            } else {
                acc0 += ubits(ur[j + 0].x) * ubits(hw4.x); acc1 += ubits(ur[j + 0].y) * ubits(hw4.x);
                acc0 += ubits(ur[j + 1].x) * ubits(hw4.y); acc1 += ubits(ur[j + 1].y) * ubits(hw4.y);
                acc0 += ubits(ur[j + 2].x) * ubits(hw4.z); acc1 += ubits(ur[j + 2].y) * ubits(hw4.z);
                acc0 += ubits(ur[j + 3].x) * ubits(hw4.w); acc1 += ubits(ur[j + 3].y) * ubits(hw4.w);
            }
        }
        *(float2*)&zpS[kq * COLSP + c0] = make_float2(acc0, acc1);
        bar_lds();          // bar1

        const unsigned int tag = (unsigned int)(t + 1);
        unsigned int* hslot = hbuf + (size_t)(t & 1) * B_ * HN + b * HN;

        if (tid < HB) {
            __builtin_amdgcn_s_setprio(1);
            // (2) issue next-step xz prefetch FIRST: latency hides under reduce
            float z4n[4];
            if (t + 1 < T_) {
#pragma unroll
                for (int g = 0; g < 4; ++g)
                    z4n[g] = xzcell[(size_t)(t + 1) * GATES + (size_t)g * HN];
            }
            float zg[4];
#pragma unroll
            for (int g = 0; g < 4; ++g) {
                float zs = z4[g];
#pragma unroll
                for (int r = 0; r < NKG; ++r) zs += zpS[r * COLSP + g * HB + tid];
                zg[g] = zs;
            }
            const float ig = fsig(zg[0]);
            const float fg = fsig(zg[1]);
            const float gg = ftanh(zg[2]);
            const float og = fsig(zg[3]);
            cst = fg * cst + ig * gg;
            const float hnew = og * ftanh(cst);

            if (t == T_ - 1) {
                __builtin_amdgcn_s_setprio(0);
                if (out_last) out_last[(size_t)b * HN + q * HB + tid] = hnew;
                if (hout) hout[((size_t)b * T_ + t) * HN + q * HB + tid] = hnew;
            } else {
                const unsigned short h16 = f2h_bits(hnew);
                // (1) publish FIRST -- siblings are spinning on this word
                __hip_atomic_store(&hslot[q * HB + tid],
                                   ((unsigned int)tag << 16) | (unsigned int)h16,
                                   __ATOMIC_RELAXED, __HIP_MEMORY_SCOPE_AGENT);
                if constexpr (F16) {
                    reinterpret_cast<unsigned short*>(hW)[q * HB + tid] = h16;
                } else {
                    hW[q * HB + tid] = __builtin_bit_cast(unsigned int, hnew);
                }
                __builtin_amdgcn_s_setprio(0);
                if (hout) hout[((size_t)b * T_ + t) * HN + q * HB + tid] = hnew;
            }
            if (t + 1 < T_) {
#pragma unroll
                for (int g = 0; g < 4; ++g) z4[g] = z4n[g];
            }
        } else if (tid >= 64 && tid < 64 + NR && t < T_ - 1) {
            const int idx = tid - 64;
            const int qp0 = q * (HB / 2);
            const int p = idx + (idx >= qp0 ? (HB / 2) : 0);   // remote pair index
            const unsigned long long* hq = (const unsigned long long*)hslot;
            unsigned long long v = __hip_atomic_load(&hq[p],
                __ATOMIC_RELAXED, __HIP_MEMORY_SCOPE_AGENT);
            while (((v >> 16) & 0xffffu) != tag || (v >> 48) != tag)
                v = __hip_atomic_load(&hq[p],
                    __ATOMIC_RELAXED, __HIP_MEMORY_SCOPE_AGENT);
            if constexpr (F16) {
                hW[p] = (unsigned int)(v & 0xffffu) |
                        ((unsigned int)((v >> 32) & 0xffffu) << 16);
            } else {
                hW[2 * p + 0] = __builtin_bit_cast(unsigned int, h2f_bits((unsigned int)v));
                hW[2 * p + 1] = __builtin_bit_cast(unsigned int, h2f_bits((unsigned int)(v >> 32)));
            }
        }
        bar_lds();          // bar2
    }
}

// ---------------------------------------------------------------------------
// LSTM recurrence v18c = v18-full (r9/r12: ~470us) + prefetch-before-reduce
// + setprio around the cell section. Structure unchanged.
// ---------------------------------------------------------------------------
__global__ __launch_bounds__(1024, 4) void lstm_full_v18c(
    const float* __restrict__ xz,       // [B, T, 512]
    const float* __restrict__ U,        // [128, 512]
    float* __restrict__ out_last)       // [B, 128]
{
    constexpr int HN = 128;
    constexpr int GATES = 512;
    constexpr int COLS = 512;           // all 4 gates x 128 units
    constexpr int CP = COLS / 2;        // 256 col-pairs
    constexpr int NKG = 1024 / CP;      // 4 k-groups
    constexpr int KH = HN / NKG;        // 32 k per group
    constexpr int WPT = KH;             // 32 ur entries (f32 pairs)
    constexpr int KWORDS = HN;          // 128 f32 h words
    constexpr int COLSP = COLS + 2;     // 514

    __shared__ __align__(16) unsigned int hW[KWORDS];
    __shared__ __align__(16) float zpS[NKG * COLSP];

    const int tid = threadIdx.x;
    const int b = blockIdx.x;           // batch element

    const int cp = tid % CP;
    const int kq = tid / CP;            // wave-uniform (CP = 256)
    const int c0 = 2 * cp;              // local col == global gate-col
    const int wbase = kq * WPT;

    // ---- one-time: U slice into registers (2 cols x 32 k = 64 f32), PIN ----
    uint2 ur[WPT];
#pragma unroll
    for (int j = 0; j < WPT; ++j) {
        const int w = wbase + j;
        const float2 r0 = *(const float2*)(U + (size_t)w * GATES + c0);
        ur[j].x = __builtin_bit_cast(unsigned int, r0.x);
        ur[j].y = __builtin_bit_cast(unsigned int, r0.y);
    }
#pragma unroll
    for (int j = 0; j < WPT; ++j)
        asm volatile("" : "+v"(ur[j].x), "+v"(ur[j].y));

    if (tid < KWORDS) hW[tid] = 0u;     // h_0 = 0
    float cst = 0.f;

    // cell lane: thread u (< 128) owns unit u; xz cols g*128 + u
    const float* xzcell = xz + (size_t)b * T_ * GATES + tid;
    float z4[4] = {0.f, 0.f, 0.f, 0.f};
    if (tid < HN) {
#pragma unroll
        for (int g = 0; g < 4; ++g) z4[g] = xzcell[g * HN];   // t=0
    }
    __syncthreads();   // one-time init barrier

#pragma unroll 1
    for (int t = 0; t < T_; ++t) {
        // ---- phase A: dot over this thread's 32 k (U in regs, h in LDS) ----
        float acc0 = 0.f, acc1 = 0.f;
#pragma unroll
        for (int j = 0; j < WPT; j += 4) {
            const int w = wbase + j;
            const uint4 hw4 = *(const uint4*)&hW[w];    // wave-uniform broadcast
            acc0 += ubits(ur[j + 0].x) * ubits(hw4.x); acc1 += ubits(ur[j + 0].y) * ubits(hw4.x);
            acc0 += ubits(ur[j + 1].x) * ubits(hw4.y); acc1 += ubits(ur[j + 1].y) * ubits(hw4.y);
            acc0 += ubits(ur[j + 2].x) * ubits(hw4.z); acc1 += ubits(ur[j + 2].y) * ubits(hw4.z);
            acc0 += ubits(ur[j + 3].x) * ubits(hw4.w); acc1 += ubits(ur[j + 3].y) * ubits(hw4.w);
        }
        *(float2*)&zpS[kq * COLSP + c0] = make_float2(acc0, acc1);
        bar_lds();          // bar1

        // ---- phase B: cell update (threads < 128), h stays in LDS ----
        if (tid < HN) {
            __builtin_amdgcn_s_setprio(1);
            float z4n[4];
            if (t + 1 < T_) {   // prefetch first: latency hides under reduce
#pragma unroll
                for (int g = 0; g < 4; ++g)
                    z4n[g] = xzcell[(size_t)(t + 1) * GATES + g * HN];
            }
            float zg[4];
#pragma unroll
            for (int g = 0; g < 4; ++g) {
                float zs = z4[g];
#pragma unroll
                for (int r = 0; r < NKG; ++r) zs += zpS[r * COLSP + g * HN + tid];
                zg[g] = zs;
            }
            const float ig = fsig(zg[0]);
            const float fg = fsig(zg[1]);
            const float gg = ftanh(zg[2]);
            const float og = fsig(zg[3]);
            cst = fg * cst + ig * gg;
            const float hnew = og * ftanh(cst);

            if (t == T_ - 1) {
                out_last[(size_t)b * HN + tid] = hnew;
            } else {
                hW[tid] = __builtin_bit_cast(unsigned int, hnew);
            }
            __builtin_amdgcn_s_setprio(0);
            if (t + 1 < T_) {
#pragma unroll
                for (int g = 0; g < 4; ++g) z4[g] = z4n[g];
            }
        }
        bar_lds();          // bar2 -> next dot sees h(t+1)
    }
}

// ---------------------------------------------------------------------------
// Launch
// ---------------------------------------------------------------------------
extern "C" void kernel_launch(void* const* d_in, const int* in_sizes, int n_in,
                              void* d_out, int out_size, void* d_ws, size_t ws_size,
                              hipStream_t stream)
{
    const float* x  = (const float*)d_in[0];
    const float* W0 = (const float*)d_in[1];
    const float* U0 = (const float*)d_in[2];
    const float* b0 = (const float*)d_in[3];
    const float* W1 = (const float*)d_in[4];
    const float* U1 = (const float*)d_in[5];
    const float* b1 = (const float*)d_in[6];
    const float* W2 = (const float*)d_in[7];
    const float* U2 = (const float*)d_in[8];
    const float* b2 = (const float*)d_in[9];
    const float* m0 = (const float*)d_in[10];
    const float* m1 = (const float*)d_in[11];
    const float* m2 = (const float*)d_in[12];
    float* out = (float*)d_out;

    // workspace layout:
    //   xz    : 134217728 B   (64*512*1024 floats, reused by all 3 layers)
    //   h0    :  33554432 B
    //   h1    :  33554432 B
    //   hbuf  : 2 regions x 131072 B (2 x 64 x 256 tagged words per layer)
    char* ws = (char*)d_ws;
    float* xz = (float*)ws;
    float* h0 = (float*)(ws + 134217728);
    float* h1 = (float*)(ws + 134217728 + 33554432);
    unsigned int* hb0 = (unsigned int*)(ws + 134217728 + 2 * 33554432);
    unsigned int* hb1 = hb0 + 2 * B_ * 256;

    const int M = B_ * T_;  // 32768

    // Layer 0
    gemm_mask_mfma<<<dim3(1024 / 128, M / 128), 256, 0, stream>>>(x, W0, b0, m0, xz, M, 1024, 128);
    lstm_rec_v21<256, true><<<256, 1024, 0, stream>>>(xz, U0, h0, nullptr, hb0);

    // Layer 1
    gemm_mask_mfma<<<dim3(1024 / 128, M / 128), 256, 0, stream>>>(h0, W1, b1, m1, xz, M, 1024, 256);
    lstm_rec_v21<256, true><<<256, 1024, 0, stream>>>(xz, U1, h1, nullptr, hb1);

    // Layer 2 (H=128): one block per batch, NO exchange, h in LDS
    gemm_mask_mfma<<<dim3(512 / 128, M / 128), 256, 0, stream>>>(h1, W2, b2, m2, xz, M, 512, 256);
    lstm_full_v18c<<<64, 1024, 0, stream>>>(xz, U2, out);
}

// Round 15
// 1976.736 us; speedup vs baseline: 1.1871x; 1.1871x over previous
//
#include <hip/hip_runtime.h>
#include <hip/hip_fp16.h>
#include <math.h>

#define B_ 64
#define T_ 512

typedef _Float16 h2_t __attribute__((ext_vector_type(2)));
typedef _Float16 f16x8 __attribute__((ext_vector_type(8)));
typedef float f32x4 __attribute__((ext_vector_type(4)));

__device__ __forceinline__ float fdot2u(unsigned int a, unsigned int b, float c) {
#if __has_builtin(__builtin_amdgcn_fdot2)
    return __builtin_amdgcn_fdot2(__builtin_bit_cast(h2_t, a),
                                  __builtin_bit_cast(h2_t, b), c, false);
#else
    const __half2 ah = __builtin_bit_cast(__half2, a);
    const __half2 bh = __builtin_bit_cast(__half2, b);
    const float2 af = __half22float2(ah), bf = __half22float2(bh);
    return c + af.x * bf.x + af.y * bf.y;
#endif
}
__device__ __forceinline__ unsigned int pack_h2(float x, float y) {
    const __half2 h = __float22half2_rn(make_float2(x, y));
    return __builtin_bit_cast(unsigned int, h);
}
__device__ __forceinline__ float ubits(unsigned int a) { return __builtin_bit_cast(float, a); }
__device__ __forceinline__ unsigned short f2h_bits(float x) {
    return __builtin_bit_cast(unsigned short, (_Float16)x);
}
__device__ __forceinline__ float h2f_bits(unsigned int bits) {
    return (float)__builtin_bit_cast(_Float16, (unsigned short)(bits & 0xffffu));
}

__device__ __forceinline__ float fsig(float z) { return 1.f / (1.f + __expf(-z)); }
__device__ __forceinline__ float ftanh(float z) {
    const float e = __expf(2.f * z);
    return 1.f - 2.f / (e + 1.f);
}

// LDS-only barrier: lgkmcnt(0) + s_barrier, no vmcnt drain (v12-proven).
__device__ __forceinline__ void bar_lds() {
    asm volatile("s_waitcnt lgkmcnt(0)" ::: "memory");
    __builtin_amdgcn_s_barrier();
    asm volatile("" ::: "memory");
}

// ---------------------------------------------------------------------------
// GEMM v3 (MFMA, r13-verified: ~30us/dispatch): C = (A*mask)@W + bias.
// 128x128 tile, 4 waves (64x64 quadrant), K-step 32, mfma_f32_16x16x32_f16.
// UNCHANGED from r13.
// ---------------------------------------------------------------------------
__global__ __launch_bounds__(256) void gemm_mask_mfma(
    const float* __restrict__ A, const float* __restrict__ W,
    const float* __restrict__ bias, const float* __restrict__ mask,
    float* __restrict__ C, int M, int N, int K)
{
    __shared__ __align__(16) unsigned int AsT[128][20];
    __shared__ __align__(16) unsigned int BsT[128][20];

    const int tid = threadIdx.x;
    const int bn = blockIdx.x;          // N/128
    const int bm = blockIdx.y;          // M/128
    const int row0 = bm * 128;
    const int col0 = bn * 128;
    const int b = row0 / T_;            // 128-row tile stays inside one batch elem

    const int wave = tid >> 6;
    const int lane = tid & 63;
    const int wm = (wave >> 1) * 64;    // wave quadrant row offset
    const int wn = (wave & 1) * 64;     // wave quadrant col offset
    const int lr = lane & 15;           // fragment row/col
    const int g  = lane >> 4;           // k-group 0..3

    f32x4 acc[4][4];
#pragma unroll
    for (int i = 0; i < 4; ++i)
#pragma unroll
        for (int j = 0; j < 4; ++j) acc[i][j] = (f32x4){0.f, 0.f, 0.f, 0.f};

    for (int kk = 0; kk < K; kk += 32) {
        // ---- stage A*mask: thread (m = tid>>1, half = tid&1 -> 16 k) ----
        {
            const int m = tid >> 1;
            const int half = tid & 1;
            const float* ap = A + (size_t)(row0 + m) * K + kk + half * 16;
            const float* mp = mask + (size_t)b * K + kk + half * 16;
            const float4 a0 = *(const float4*)(ap);
            const float4 a1 = *(const float4*)(ap + 4);
            const float4 a2 = *(const float4*)(ap + 8);
            const float4 a3 = *(const float4*)(ap + 12);
            const float4 m0 = *(const float4*)(mp);
            const float4 m1 = *(const float4*)(mp + 4);
            const float4 m2 = *(const float4*)(mp + 8);
            const float4 m3 = *(const float4*)(mp + 12);
            uint4 lo, hi;
            lo.x = pack_h2(a0.x * m0.x, a0.y * m0.y);
            lo.y = pack_h2(a0.z * m0.z, a0.w * m0.w);
            lo.z = pack_h2(a1.x * m1.x, a1.y * m1.y);
            lo.w = pack_h2(a1.z * m1.z, a1.w * m1.w);
            hi.x = pack_h2(a2.x * m2.x, a2.y * m2.y);
            hi.y = pack_h2(a2.z * m2.z, a2.w * m2.w);
            hi.z = pack_h2(a3.x * m3.x, a3.y * m3.y);
            hi.w = pack_h2(a3.z * m3.z, a3.w * m3.w);
            *(uint4*)&AsT[m][half * 8 + 0] = lo;   // 80B row stride: 16B-aligned
            *(uint4*)&AsT[m][half * 8 + 4] = hi;
        }
        // ---- stage B (W k-pair transposed) ----
        {
            const int kp = tid >> 4;
            const int t15 = tid & 15;
            const float* w0p = W + (size_t)(kk + 2 * kp) * N + col0 + t15;
            const float* w1p = W + (size_t)(kk + 2 * kp + 1) * N + col0 + t15;
#pragma unroll
            for (int i = 0; i < 8; ++i) {
                const int n = t15 + 16 * i;
                BsT[n][kp] = pack_h2(w0p[16 * i], w1p[16 * i]);
            }
        }
        __syncthreads();

        // ---- fragments + 16 MFMA per wave ----
        f16x8 af[4], bf[4];
#pragma unroll
        for (int i = 0; i < 4; ++i)
            af[i] = __builtin_bit_cast(f16x8, *(const uint4*)&AsT[wm + 16 * i + lr][g * 4]);
#pragma unroll
        for (int j = 0; j < 4; ++j)
            bf[j] = __builtin_bit_cast(f16x8, *(const uint4*)&BsT[wn + 16 * j + lr][g * 4]);
#pragma unroll
        for (int i = 0; i < 4; ++i)
#pragma unroll
            for (int j = 0; j < 4; ++j)
                acc[i][j] = __builtin_amdgcn_mfma_f32_16x16x32_f16(af[i], bf[j], acc[i][j], 0, 0, 0);
        __syncthreads();
    }

    // ---- epilogue: C/D mapping col = lane&15, row = (lane>>4)*4 + reg ----
#pragma unroll
    for (int j = 0; j < 4; ++j) {
        const int c = col0 + wn + 16 * j + lr;
        const float bv = bias[c];
#pragma unroll
        for (int i = 0; i < 4; ++i) {
            const int r0 = row0 + wm + 16 * i + g * 4;
            C[(size_t)(r0 + 0) * N + c] = acc[i][j][0] + bv;
            C[(size_t)(r0 + 1) * N + c] = acc[i][j][1] + bv;
            C[(size_t)(r0 + 2) * N + c] = acc[i][j][2] + bv;
            C[(size_t)(r0 + 3) * N + c] = acc[i][j][3] + bv;
        }
    }
}

// ---------------------------------------------------------------------------
// LSTM recurrence v16 (r9/r12/r13-verified best: ~698us/dispatch): v13
// 2-phase structure + pinned-register U + conflict-free zpart. 4-way split,
// tagged L2 exchange. Lessons encoded: (r8) INLINE phase bodies only;
// (r10) 2-way split regresses; (r11) readlane hW regresses; (r14) cell-phase
// reordering + setprio regresses (priority is zero-sum vs poll waves;
// compiler's default cell schedule is already optimal). UNCHANGED from r13.
// ---------------------------------------------------------------------------
template <int HN, bool F16>
__global__ __launch_bounds__(1024, 4) void lstm_rec_v16(
    const float* __restrict__ xz,       // [B, T, 4*HN]
    const float* __restrict__ U,        // [HN, 4*HN]
    float* __restrict__ hout,           // [B, T, HN] or nullptr
    float* __restrict__ out_last,       // [B, HN] or nullptr
    unsigned int* __restrict__ hbuf)    // [2][B_*HN] tagged words
{
    constexpr int GATES = 4 * HN;
    constexpr int COLS = HN;
    constexpr int CP = COLS / 2;
    constexpr int NKG = 1024 / CP;
    constexpr int KH = HN / NKG;
    constexpr int HB = HN / 4;
    constexpr int KWORDS = F16 ? HN / 2 : HN;
    constexpr int WPT = F16 ? KH / 2 : KH;
    constexpr int COLSP = COLS + 2;
    constexpr int NR = 3 * HB / 2;

    __shared__ __align__(16) unsigned int hW[KWORDS];
    __shared__ __align__(16) float zpS[NKG * COLSP];

    const int tid = threadIdx.x;
    const int q = blockIdx.x >> 6;      // quarter 0..3
    const int b = blockIdx.x & 63;      // batch element (siblings 64 apart -> same XCD)

    const int cp = tid % CP;
    const int kq = tid / CP;            // wave-uniform (CP % 64 == 0)
    const int c0 = 2 * cp;
    const int group = c0 / HB;
    const int gcol = group * HN + q * HB + (c0 % HB);
    const int wbase = kq * WPT;

    // ---- one-time: load this thread's U slice into REGISTERS, then PIN ----
    uint2 ur[WPT];
#pragma unroll
    for (int j = 0; j < WPT; ++j) {
        const int w = wbase + j;
        if constexpr (F16) {
            const float2 r0 = *(const float2*)(U + (size_t)(2 * w) * GATES + gcol);
            const float2 r1 = *(const float2*)(U + (size_t)(2 * w + 1) * GATES + gcol);
            ur[j].x = pack_h2(r0.x, r1.x);
            ur[j].y = pack_h2(r0.y, r1.y);
        } else {
            const float2 r0 = *(const float2*)(U + (size_t)w * GATES + gcol);
            ur[j].x = __builtin_bit_cast(unsigned int, r0.x);
            ur[j].y = __builtin_bit_cast(unsigned int, r0.y);
        }
    }
#pragma unroll
    for (int j = 0; j < WPT; ++j)
        asm volatile("" : "+v"(ur[j].x), "+v"(ur[j].y));

    if (tid < KWORDS) hW[tid] = 0u;     // h_0 = 0
    float cst = 0.f;

    const float* xzcell = xz + (size_t)b * T_ * GATES + q * HB + tid;
    float z4[4] = {0.f, 0.f, 0.f, 0.f};
    if (tid < HB) {
#pragma unroll
        for (int g = 0; g < 4; ++g) z4[g] = xzcell[(size_t)g * HN];   // t=0
    }
    __syncthreads();   // one-time init barrier

#pragma unroll 1
    for (int t = 0; t < T_; ++t) {
        // ---- phase A: dot (U in regs, h from LDS) ----
        float acc0 = 0.f, acc1 = 0.f;
#pragma unroll
        for (int j = 0; j < WPT; j += 4) {
            const int w = wbase + j;
            const uint4 hw4 = *(const uint4*)&hW[w];    // wave-uniform broadcast
            if constexpr (F16) {
                acc0 = fdot2u(ur[j + 0].x, hw4.x, acc0); acc1 = fdot2u(ur[j + 0].y, hw4.x, acc1);
                acc0 = fdot2u(ur[j + 1].x, hw4.y, acc0); acc1 = fdot2u(ur[j + 1].y, hw4.y, acc1);
                acc0 = fdot2u(ur[j + 2].x, hw4.z, acc0); acc1 = fdot2u(ur[j + 2].y, hw4.z, acc1);
                acc0 = fdot2u(ur[j + 3].x, hw4.w, acc0); acc1 = fdot2u(ur[j + 3].y, hw4.w, acc1);
            } else {
                acc0 += ubits(ur[j + 0].x) * ubits(hw4.x); acc1 += ubits(ur[j + 0].y) * ubits(hw4.x);
                acc0 += ubits(ur[j + 1].x) * ubits(hw4.y); acc1 += ubits(ur[j + 1].y) * ubits(hw4.y);
                acc0 += ubits(ur[j + 2].x) * ubits(hw4.z); acc1 += ubits(ur[j + 2].y) * ubits(hw4.z);
                acc0 += ubits(ur[j + 3].x) * ubits(hw4.w); acc1 += ubits(ur[j + 3].y) * ubits(hw4.w);
            }
        }
        *(float2*)&zpS[kq * COLSP + c0] = make_float2(acc0, acc1);
        bar_lds();          // bar1

        const unsigned int tag = (unsigned int)(t + 1);
        unsigned int* hslot = hbuf + (size_t)(t & 1) * B_ * HN + b * HN;

        if (tid < HB) {
            float zg[4];
#pragma unroll
            for (int g = 0; g < 4; ++g) {
                float zs = z4[g];
#pragma unroll
                for (int r = 0; r < NKG; ++r) zs += zpS[r * COLSP + g * HB + tid];
                zg[g] = zs;
            }
            if (t + 1 < T_) {
#pragma unroll
                for (int g = 0; g < 4; ++g)
                    z4[g] = xzcell[(size_t)(t + 1) * GATES + (size_t)g * HN];
            }
            const float ig = fsig(zg[0]);
            const float fg = fsig(zg[1]);
            const float gg = ftanh(zg[2]);
            const float og = fsig(zg[3]);
            cst = fg * cst + ig * gg;
            const float hnew = og * ftanh(cst);

            if (hout) hout[((size_t)b * T_ + t) * HN + q * HB + tid] = hnew;
            if (t == T_ - 1) {
                if (out_last) out_last[(size_t)b * HN + q * HB + tid] = hnew;
            } else {
                const unsigned short h16 = f2h_bits(hnew);
                __hip_atomic_store(&hslot[q * HB + tid],
                                   ((unsigned int)tag << 16) | (unsigned int)h16,
                                   __ATOMIC_RELAXED, __HIP_MEMORY_SCOPE_AGENT);
                if constexpr (F16) {
                    reinterpret_cast<unsigned short*>(hW)[q * HB + tid] = h16;
                } else {
                    hW[q * HB + tid] = __builtin_bit_cast(unsigned int, hnew);
                }
            }
        } else if (tid >= 64 && tid < 64 + NR && t < T_ - 1) {
            const int idx = tid - 64;
            const int qp0 = q * (HB / 2);
            const int p = idx + (idx >= qp0 ? (HB / 2) : 0);   // remote pair index
            const unsigned long long* hq = (const unsigned long long*)hslot;
            unsigned long long v = __hip_atomic_load(&hq[p],
                __ATOMIC_RELAXED, __HIP_MEMORY_SCOPE_AGENT);
            while (((v >> 16) & 0xffffu) != tag || (v >> 48) != tag)
                v = __hip_atomic_load(&hq[p],
                    __ATOMIC_RELAXED, __HIP_MEMORY_SCOPE_AGENT);
            if constexpr (F16) {
                hW[p] = (unsigned int)(v & 0xffffu) |
                        ((unsigned int)((v >> 32) & 0xffffu) << 16);
            } else {
                hW[2 * p + 0] = __builtin_bit_cast(unsigned int, h2f_bits((unsigned int)v));
                hW[2 * p + 1] = __builtin_bit_cast(unsigned int, h2f_bits((unsigned int)(v >> 32)));
            }
        }
        bar_lds();          // bar2
    }
}

// ---------------------------------------------------------------------------
// LSTM recurrence v18-full (r9/r12/r13-verified: ~470us): ONE block per
// batch element, NO exchange, h entirely in LDS. UNCHANGED from r13.
// ---------------------------------------------------------------------------
__global__ __launch_bounds__(1024, 4) void lstm_full_v18(
    const float* __restrict__ xz,       // [B, T, 512]
    const float* __restrict__ U,        // [128, 512]
    float* __restrict__ out_last)       // [B, 128]
{
    constexpr int HN = 128;
    constexpr int GATES = 512;
    constexpr int COLS = 512;           // all 4 gates x 128 units
    constexpr int CP = COLS / 2;        // 256 col-pairs
    constexpr int NKG = 1024 / CP;      // 4 k-groups
    constexpr int KH = HN / NKG;        // 32 k per group
    constexpr int WPT = KH;             // 32 ur entries (f32 pairs)
    constexpr int KWORDS = HN;          // 128 f32 h words
    constexpr int COLSP = COLS + 2;     // 514

    __shared__ __align__(16) unsigned int hW[KWORDS];
    __shared__ __align__(16) float zpS[NKG * COLSP];

    const int tid = threadIdx.x;
    const int b = blockIdx.x;           // batch element

    const int cp = tid % CP;
    const int kq = tid / CP;            // wave-uniform (CP = 256)
    const int c0 = 2 * cp;              // local col == global gate-col
    const int wbase = kq * WPT;

    // ---- one-time: U slice into registers (2 cols x 32 k = 64 f32), PIN ----
    uint2 ur[WPT];
#pragma unroll
    for (int j = 0; j < WPT; ++j) {
        const int w = wbase + j;
        const float2 r0 = *(const float2*)(U + (size_t)w * GATES + c0);
        ur[j].x = __builtin_bit_cast(unsigned int, r0.x);
        ur[j].y = __builtin_bit_cast(unsigned int, r0.y);
    }
#pragma unroll
    for (int j = 0; j < WPT; ++j)
        asm volatile("" : "+v"(ur[j].x), "+v"(ur[j].y));

    if (tid < KWORDS) hW[tid] = 0u;     // h_0 = 0
    float cst = 0.f;

    // cell lane: thread u (< 128) owns unit u; xz cols g*128 + u
    const float* xzcell = xz + (size_t)b * T_ * GATES + tid;
    float z4[4] = {0.f, 0.f, 0.f, 0.f};
    if (tid < HN) {
#pragma unroll
        for (int g = 0; g < 4; ++g) z4[g] = xzcell[g * HN];   // t=0
    }
    __syncthreads();   // one-time init barrier

#pragma unroll 1
    for (int t = 0; t < T_; ++t) {
        // ---- phase A: dot over this thread's 32 k (U in regs, h in LDS) ----
        float acc0 = 0.f, acc1 = 0.f;
#pragma unroll
        for (int j = 0; j < WPT; j += 4) {
            const int w = wbase + j;
            const uint4 hw4 = *(const uint4*)&hW[w];    // wave-uniform broadcast
            acc0 += ubits(ur[j + 0].x) * ubits(hw4.x); acc1 += ubits(ur[j + 0].y) * ubits(hw4.x);
            acc0 += ubits(ur[j + 1].x) * ubits(hw4.y); acc1 += ubits(ur[j + 1].y) * ubits(hw4.y);
            acc0 += ubits(ur[j + 2].x) * ubits(hw4.z); acc1 += ubits(ur[j + 2].y) * ubits(hw4.z);
            acc0 += ubits(ur[j + 3].x) * ubits(hw4.w); acc1 += ubits(ur[j + 3].y) * ubits(hw4.w);
        }
        *(float2*)&zpS[kq * COLSP + c0] = make_float2(acc0, acc1);
        bar_lds();          // bar1

        // ---- phase B: cell update (threads < 128), h stays in LDS ----
        if (tid < HN) {
            float zg[4];
#pragma unroll
            for (int g = 0; g < 4; ++g) {
                float zs = z4[g];
#pragma unroll
                for (int r = 0; r < NKG; ++r) zs += zpS[r * COLSP + g * HN + tid];
                zg[g] = zs;
            }
            if (t + 1 < T_) {   // prefetch next xz
#pragma unroll
                for (int g = 0; g < 4; ++g)
                    z4[g] = xzcell[(size_t)(t + 1) * GATES + g * HN];
            }
            const float ig = fsig(zg[0]);
            const float fg = fsig(zg[1]);
            const float gg = ftanh(zg[2]);
            const float og = fsig(zg[3]);
            cst = fg * cst + ig * gg;
            const float hnew = og * ftanh(cst);

            if (t == T_ - 1) {
                out_last[(size_t)b * HN + tid] = hnew;
            } else {
                hW[tid] = __builtin_bit_cast(unsigned int, hnew);
            }
        }
        bar_lds();          // bar2 -> next dot sees h(t+1)
    }
}

// ---------------------------------------------------------------------------
// Launch
// ---------------------------------------------------------------------------
extern "C" void kernel_launch(void* const* d_in, const int* in_sizes, int n_in,
                              void* d_out, int out_size, void* d_ws, size_t ws_size,
                              hipStream_t stream)
{
    const float* x  = (const float*)d_in[0];
    const float* W0 = (const float*)d_in[1];
    const float* U0 = (const float*)d_in[2];
    const float* b0 = (const float*)d_in[3];
    const float* W1 = (const float*)d_in[4];
    const float* U1 = (const float*)d_in[5];
    const float* b1 = (const float*)d_in[6];
    const float* W2 = (const float*)d_in[7];
    const float* U2 = (const float*)d_in[8];
    const float* b2 = (const float*)d_in[9];
    const float* m0 = (const float*)d_in[10];
    const float* m1 = (const float*)d_in[11];
    const float* m2 = (const float*)d_in[12];
    float* out = (float*)d_out;

    // workspace layout:
    //   xz    : 134217728 B   (64*512*1024 floats, reused by all 3 layers)
    //   h0    :  33554432 B
    //   h1    :  33554432 B
    //   hbuf  : 2 regions x 131072 B (2 x 64 x 256 tagged words per layer)
    char* ws = (char*)d_ws;
    float* xz = (float*)ws;
    float* h0 = (float*)(ws + 134217728);
    float* h1 = (float*)(ws + 134217728 + 33554432);
    unsigned int* hb0 = (unsigned int*)(ws + 134217728 + 2 * 33554432);
    unsigned int* hb1 = hb0 + 2 * B_ * 256;

    const int M = B_ * T_;  // 32768

    // Layer 0
    gemm_mask_mfma<<<dim3(1024 / 128, M / 128), 256, 0, stream>>>(x, W0, b0, m0, xz, M, 1024, 128);
    lstm_rec_v16<256, true><<<256, 1024, 0, stream>>>(xz, U0, h0, nullptr, hb0);

    // Layer 1
    gemm_mask_mfma<<<dim3(1024 / 128, M / 128), 256, 0, stream>>>(h0, W1, b1, m1, xz, M, 1024, 256);
    lstm_rec_v16<256, true><<<256, 1024, 0, stream>>>(xz, U1, h1, nullptr, hb1);

    // Layer 2 (H=128): one block per batch, NO exchange, h in LDS
    gemm_mask_mfma<<<dim3(512 / 128, M / 128), 256, 0, stream>>>(h1, W2, b2, m2, xz, M, 512, 256);
    lstm_full_v18<<<64, 1024, 0, stream>>>(xz, U2, out);
}

// Round 16
// 1896.468 us; speedup vs baseline: 1.2374x; 1.0423x over previous
//
#include <hip/hip_runtime.h>
#include <hip/hip_fp16.h>
#include <math.h>

#define B_ 64
#define T_ 512

typedef _Float16 h2_t __attribute__((ext_vector_type(2)));
typedef _Float16 f16x8 __attribute__((ext_vector_type(8)));
typedef float f32x4 __attribute__((ext_vector_type(4)));

__device__ __forceinline__ float fdot2u(unsigned int a, unsigned int b, float c) {
#if __has_builtin(__builtin_amdgcn_fdot2)
    return __builtin_amdgcn_fdot2(__builtin_bit_cast(h2_t, a),
                                  __builtin_bit_cast(h2_t, b), c, false);
#else
    const __half2 ah = __builtin_bit_cast(__half2, a);
    const __half2 bh = __builtin_bit_cast(__half2, b);
    const float2 af = __half22float2(ah), bf = __half22float2(bh);
    return c + af.x * bf.x + af.y * bf.y;
#endif
}
__device__ __forceinline__ unsigned int pack_h2(float x, float y) {
    const __half2 h = __float22half2_rn(make_float2(x, y));
    return __builtin_bit_cast(unsigned int, h);
}
__device__ __forceinline__ float ubits(unsigned int a) { return __builtin_bit_cast(float, a); }
__device__ __forceinline__ unsigned short f2h_bits(float x) {
    return __builtin_bit_cast(unsigned short, (_Float16)x);
}
__device__ __forceinline__ float h2f_bits(unsigned int bits) {
    return (float)__builtin_bit_cast(_Float16, (unsigned short)(bits & 0xffffu));
}

__device__ __forceinline__ float fsig(float z) { return 1.f / (1.f + __expf(-z)); }
__device__ __forceinline__ float ftanh(float z) {
    const float e = __expf(2.f * z);
    return 1.f - 2.f / (e + 1.f);
}

// LDS-only barrier: lgkmcnt(0) + s_barrier, no vmcnt drain (v12-proven).
__device__ __forceinline__ void bar_lds() {
    asm volatile("s_waitcnt lgkmcnt(0)" ::: "memory");
    __builtin_amdgcn_s_barrier();
    asm volatile("" ::: "memory");
}

// ---------------------------------------------------------------------------
// GEMM v3 (MFMA, r13-verified: ~30us/dispatch): C = (A*mask)@W + bias.
// 128x128 tile, 4 waves (64x64 quadrant), K-step 32, mfma_f32_16x16x32_f16.
// UNCHANGED from r13.
// ---------------------------------------------------------------------------
__global__ __launch_bounds__(256) void gemm_mask_mfma(
    const float* __restrict__ A, const float* __restrict__ W,
    const float* __restrict__ bias, const float* __restrict__ mask,
    float* __restrict__ C, int M, int N, int K)
{
    __shared__ __align__(16) unsigned int AsT[128][20];
    __shared__ __align__(16) unsigned int BsT[128][20];

    const int tid = threadIdx.x;
    const int bn = blockIdx.x;          // N/128
    const int bm = blockIdx.y;          // M/128
    const int row0 = bm * 128;
    const int col0 = bn * 128;
    const int b = row0 / T_;            // 128-row tile stays inside one batch elem

    const int wave = tid >> 6;
    const int lane = tid & 63;
    const int wm = (wave >> 1) * 64;    // wave quadrant row offset
    const int wn = (wave & 1) * 64;     // wave quadrant col offset
    const int lr = lane & 15;           // fragment row/col
    const int g  = lane >> 4;           // k-group 0..3

    f32x4 acc[4][4];
#pragma unroll
    for (int i = 0; i < 4; ++i)
#pragma unroll
        for (int j = 0; j < 4; ++j) acc[i][j] = (f32x4){0.f, 0.f, 0.f, 0.f};

    for (int kk = 0; kk < K; kk += 32) {
        // ---- stage A*mask: thread (m = tid>>1, half = tid&1 -> 16 k) ----
        {
            const int m = tid >> 1;
            const int half = tid & 1;
            const float* ap = A + (size_t)(row0 + m) * K + kk + half * 16;
            const float* mp = mask + (size_t)b * K + kk + half * 16;
            const float4 a0 = *(const float4*)(ap);
            const float4 a1 = *(const float4*)(ap + 4);
            const float4 a2 = *(const float4*)(ap + 8);
            const float4 a3 = *(const float4*)(ap + 12);
            const float4 m0 = *(const float4*)(mp);
            const float4 m1 = *(const float4*)(mp + 4);
            const float4 m2 = *(const float4*)(mp + 8);
            const float4 m3 = *(const float4*)(mp + 12);
            uint4 lo, hi;
            lo.x = pack_h2(a0.x * m0.x, a0.y * m0.y);
            lo.y = pack_h2(a0.z * m0.z, a0.w * m0.w);
            lo.z = pack_h2(a1.x * m1.x, a1.y * m1.y);
            lo.w = pack_h2(a1.z * m1.z, a1.w * m1.w);
            hi.x = pack_h2(a2.x * m2.x, a2.y * m2.y);
            hi.y = pack_h2(a2.z * m2.z, a2.w * m2.w);
            hi.z = pack_h2(a3.x * m3.x, a3.y * m3.y);
            hi.w = pack_h2(a3.z * m3.z, a3.w * m3.w);
            *(uint4*)&AsT[m][half * 8 + 0] = lo;   // 80B row stride: 16B-aligned
            *(uint4*)&AsT[m][half * 8 + 4] = hi;
        }
        // ---- stage B (W k-pair transposed) ----
        {
            const int kp = tid >> 4;
            const int t15 = tid & 15;
            const float* w0p = W + (size_t)(kk + 2 * kp) * N + col0 + t15;
            const float* w1p = W + (size_t)(kk + 2 * kp + 1) * N + col0 + t15;
#pragma unroll
            for (int i = 0; i < 8; ++i) {
                const int n = t15 + 16 * i;
                BsT[n][kp] = pack_h2(w0p[16 * i], w1p[16 * i]);
            }
        }
        __syncthreads();

        // ---- fragments + 16 MFMA per wave ----
        f16x8 af[4], bf[4];
#pragma unroll
        for (int i = 0; i < 4; ++i)
            af[i] = __builtin_bit_cast(f16x8, *(const uint4*)&AsT[wm + 16 * i + lr][g * 4]);
#pragma unroll
        for (int j = 0; j < 4; ++j)
            bf[j] = __builtin_bit_cast(f16x8, *(const uint4*)&BsT[wn + 16 * j + lr][g * 4]);
#pragma unroll
        for (int i = 0; i < 4; ++i)
#pragma unroll
            for (int j = 0; j < 4; ++j)
                acc[i][j] = __builtin_amdgcn_mfma_f32_16x16x32_f16(af[i], bf[j], acc[i][j], 0, 0, 0);
        __syncthreads();
    }

    // ---- epilogue: C/D mapping col = lane&15, row = (lane>>4)*4 + reg ----
#pragma unroll
    for (int j = 0; j < 4; ++j) {
        const int c = col0 + wn + 16 * j + lr;
        const float bv = bias[c];
#pragma unroll
        for (int i = 0; i < 4; ++i) {
            const int r0 = row0 + wm + 16 * i + g * 4;
            C[(size_t)(r0 + 0) * N + c] = acc[i][j][0] + bv;
            C[(size_t)(r0 + 1) * N + c] = acc[i][j][1] + bv;
            C[(size_t)(r0 + 2) * N + c] = acc[i][j][2] + bv;
            C[(size_t)(r0 + 3) * N + c] = acc[i][j][3] + bv;
        }
    }
}

// ---------------------------------------------------------------------------
// LSTM recurrence v16 (r9/r12/r13/r15-verified best: ~708us/dispatch).
// UNCHANGED. Lessons: INLINE bodies (r8); 4-way split optimal (r10);
// broadcast b128 hW reads optimal (r11); no reordering/setprio (r14).
// ---------------------------------------------------------------------------
template <int HN, bool F16>
__global__ __launch_bounds__(1024, 4) void lstm_rec_v16(
    const float* __restrict__ xz,       // [B, T, 4*HN]
    const float* __restrict__ U,        // [HN, 4*HN]
    float* __restrict__ hout,           // [B, T, HN] or nullptr
    float* __restrict__ out_last,       // [B, HN] or nullptr
    unsigned int* __restrict__ hbuf)    // [2][B_*HN] tagged words
{
    constexpr int GATES = 4 * HN;
    constexpr int COLS = HN;
    constexpr int CP = COLS / 2;
    constexpr int NKG = 1024 / CP;
    constexpr int KH = HN / NKG;
    constexpr int HB = HN / 4;
    constexpr int KWORDS = F16 ? HN / 2 : HN;
    constexpr int WPT = F16 ? KH / 2 : KH;
    constexpr int COLSP = COLS + 2;
    constexpr int NR = 3 * HB / 2;

    __shared__ __align__(16) unsigned int hW[KWORDS];
    __shared__ __align__(16) float zpS[NKG * COLSP];

    const int tid = threadIdx.x;
    const int q = blockIdx.x >> 6;      // quarter 0..3
    const int b = blockIdx.x & 63;      // batch element (siblings 64 apart -> same XCD)

    const int cp = tid % CP;
    const int kq = tid / CP;            // wave-uniform (CP % 64 == 0)
    const int c0 = 2 * cp;
    const int group = c0 / HB;
    const int gcol = group * HN + q * HB + (c0 % HB);
    const int wbase = kq * WPT;

    // ---- one-time: load this thread's U slice into REGISTERS, then PIN ----
    uint2 ur[WPT];
#pragma unroll
    for (int j = 0; j < WPT; ++j) {
        const int w = wbase + j;
        if constexpr (F16) {
            const float2 r0 = *(const float2*)(U + (size_t)(2 * w) * GATES + gcol);
            const float2 r1 = *(const float2*)(U + (size_t)(2 * w + 1) * GATES + gcol);
            ur[j].x = pack_h2(r0.x, r1.x);
            ur[j].y = pack_h2(r0.y, r1.y);
        } else {
            const float2 r0 = *(const float2*)(U + (size_t)w * GATES + gcol);
            ur[j].x = __builtin_bit_cast(unsigned int, r0.x);
            ur[j].y = __builtin_bit_cast(unsigned int, r0.y);
        }
    }
#pragma unroll
    for (int j = 0; j < WPT; ++j)
        asm volatile("" : "+v"(ur[j].x), "+v"(ur[j].y));

    if (tid < KWORDS) hW[tid] = 0u;     // h_0 = 0
    float cst = 0.f;

    const float* xzcell = xz + (size_t)b * T_ * GATES + q * HB + tid;
    float z4[4] = {0.f, 0.f, 0.f, 0.f};
    if (tid < HB) {
#pragma unroll
        for (int g = 0; g < 4; ++g) z4[g] = xzcell[(size_t)g * HN];   // t=0
    }
    __syncthreads();   // one-time init barrier

#pragma unroll 1
    for (int t = 0; t < T_; ++t) {
        // ---- phase A: dot (U in regs, h from LDS) ----
        float acc0 = 0.f, acc1 = 0.f;
#pragma unroll
        for (int j = 0; j < WPT; j += 4) {
            const int w = wbase + j;
            const uint4 hw4 = *(const uint4*)&hW[w];    // wave-uniform broadcast
            if constexpr (F16) {
                acc0 = fdot2u(ur[j + 0].x, hw4.x, acc0); acc1 = fdot2u(ur[j + 0].y, hw4.x, acc1);
                acc0 = fdot2u(ur[j + 1].x, hw4.y, acc0); acc1 = fdot2u(ur[j + 1].y, hw4.y, acc1);
                acc0 = fdot2u(ur[j + 2].x, hw4.z, acc0); acc1 = fdot2u(ur[j + 2].y, hw4.z, acc1);
                acc0 = fdot2u(ur[j + 3].x, hw4.w, acc0); acc1 = fdot2u(ur[j + 3].y, hw4.w, acc1);
            } else {
                acc0 += ubits(ur[j + 0].x) * ubits(hw4.x); acc1 += ubits(ur[j + 0].y) * ubits(hw4.x);
                acc0 += ubits(ur[j + 1].x) * ubits(hw4.y); acc1 += ubits(ur[j + 1].y) * ubits(hw4.y);
                acc0 += ubits(ur[j + 2].x) * ubits(hw4.z); acc1 += ubits(ur[j + 2].y) * ubits(hw4.z);
                acc0 += ubits(ur[j + 3].x) * ubits(hw4.w); acc1 += ubits(ur[j + 3].y) * ubits(hw4.w);
            }
        }
        *(float2*)&zpS[kq * COLSP + c0] = make_float2(acc0, acc1);
        bar_lds();          // bar1

        const unsigned int tag = (unsigned int)(t + 1);
        unsigned int* hslot = hbuf + (size_t)(t & 1) * B_ * HN + b * HN;

        if (tid < HB) {
            float zg[4];
#pragma unroll
            for (int g = 0; g < 4; ++g) {
                float zs = z4[g];
#pragma unroll
                for (int r = 0; r < NKG; ++r) zs += zpS[r * COLSP + g * HB + tid];
                zg[g] = zs;
            }
            if (t + 1 < T_) {
#pragma unroll
                for (int g = 0; g < 4; ++g)
                    z4[g] = xzcell[(size_t)(t + 1) * GATES + (size_t)g * HN];
            }
            const float ig = fsig(zg[0]);
            const float fg = fsig(zg[1]);
            const float gg = ftanh(zg[2]);
            const float og = fsig(zg[3]);
            cst = fg * cst + ig * gg;
            const float hnew = og * ftanh(cst);

            if (hout) hout[((size_t)b * T_ + t) * HN + q * HB + tid] = hnew;
            if (t == T_ - 1) {
                if (out_last) out_last[(size_t)b * HN + q * HB + tid] = hnew;
            } else {
                const unsigned short h16 = f2h_bits(hnew);
                __hip_atomic_store(&hslot[q * HB + tid],
                                   ((unsigned int)tag << 16) | (unsigned int)h16,
                                   __ATOMIC_RELAXED, __HIP_MEMORY_SCOPE_AGENT);
                if constexpr (F16) {
                    reinterpret_cast<unsigned short*>(hW)[q * HB + tid] = h16;
                } else {
                    hW[q * HB + tid] = __builtin_bit_cast(unsigned int, hnew);
                }
            }
        } else if (tid >= 64 && tid < 64 + NR && t < T_ - 1) {
            const int idx = tid - 64;
            const int qp0 = q * (HB / 2);
            const int p = idx + (idx >= qp0 ? (HB / 2) : 0);   // remote pair index
            const unsigned long long* hq = (const unsigned long long*)hslot;
            unsigned long long v = __hip_atomic_load(&hq[p],
                __ATOMIC_RELAXED, __HIP_MEMORY_SCOPE_AGENT);
            while (((v >> 16) & 0xffffu) != tag || (v >> 48) != tag)
                v = __hip_atomic_load(&hq[p],
                    __ATOMIC_RELAXED, __HIP_MEMORY_SCOPE_AGENT);
            if constexpr (F16) {
                hW[p] = (unsigned int)(v & 0xffffu) |
                        ((unsigned int)((v >> 32) & 0xffffu) << 16);
            } else {
                hW[2 * p + 0] = __builtin_bit_cast(unsigned int, h2f_bits((unsigned int)v));
                hW[2 * p + 1] = __builtin_bit_cast(unsigned int, h2f_bits((unsigned int)(v >> 32)));
            }
        }
        bar_lds();          // bar2
    }
}

// ---------------------------------------------------------------------------
// LSTM recurrence v18d = v18-full with the dot converted from f32 fma to
// packed-f16 fdot2 (v16's proven pattern). r15 model: v19's +100us regression
// is exactly the doubled dot-issue (+256cy/SIMD/step) -> dot VALU issue is
// the lever, broadcasts are cheap. v18's f32 dot = 64 fma/thread = 512cy/
// SIMD/step issue, the largest priced term in its ~2200cy step. f16 dot:
// 32 fdot2 + 4 b128/thread (half of both). hW = k-pair-packed f16 (64 words);
// cell stores h as ushort (same idiom as v16 F16 local write); out_last f32.
// Everything else identical to v18.
// ---------------------------------------------------------------------------
__global__ __launch_bounds__(1024, 4) void lstm_full_v18d(
    const float* __restrict__ xz,       // [B, T, 512]
    const float* __restrict__ U,        // [128, 512]
    float* __restrict__ out_last)       // [B, 128]
{
    constexpr int HN = 128;
    constexpr int GATES = 512;
    constexpr int COLS = 512;           // all 4 gates x 128 units
    constexpr int CP = COLS / 2;        // 256 col-pairs
    constexpr int NKG = 1024 / CP;      // 4 k-groups
    constexpr int KH = HN / NKG;        // 32 k per group
    constexpr int WPT = KH / 2;         // 16 uint2 entries (one per k-pair)
    constexpr int KWORDS = HN / 2;      // 64 hW words (f16 pairs over k)
    constexpr int COLSP = COLS + 2;     // 514

    __shared__ __align__(16) unsigned int hW[KWORDS];
    __shared__ __align__(16) float zpS[NKG * COLSP];

    const int tid = threadIdx.x;
    const int b = blockIdx.x;           // batch element

    const int cp = tid % CP;
    const int kq = tid / CP;            // wave-uniform (CP = 256)
    const int c0 = 2 * cp;              // local col == global gate-col
    const int wbase = kq * WPT;         // k-pair base (kq*16)

    // ---- one-time: U slice into registers (f16-packed over k-pairs), PIN ----
    uint2 ur[WPT];
#pragma unroll
    for (int j = 0; j < WPT; ++j) {
        const int w = wbase + j;        // k-pair index
        const float2 r0 = *(const float2*)(U + (size_t)(2 * w) * GATES + c0);
        const float2 r1 = *(const float2*)(U + (size_t)(2 * w + 1) * GATES + c0);
        ur[j].x = pack_h2(r0.x, r1.x);  // col c0:   {U[2w], U[2w+1]}
        ur[j].y = pack_h2(r0.y, r1.y);  // col c0+1: {U[2w], U[2w+1]}
    }
#pragma unroll
    for (int j = 0; j < WPT; ++j)
        asm volatile("" : "+v"(ur[j].x), "+v"(ur[j].y));

    if (tid < KWORDS) hW[tid] = 0u;     // h_0 = 0 (f16 zeros)
    float cst = 0.f;

    // cell lane: thread u (< 128) owns unit u; xz cols g*128 + u
    const float* xzcell = xz + (size_t)b * T_ * GATES + tid;
    float z4[4] = {0.f, 0.f, 0.f, 0.f};
    if (tid < HN) {
#pragma unroll
        for (int g = 0; g < 4; ++g) z4[g] = xzcell[g * HN];   // t=0
    }
    __syncthreads();   // one-time init barrier

#pragma unroll 1
    for (int t = 0; t < T_; ++t) {
        // ---- phase A: dot over this thread's 16 k-pairs (fdot2, h in LDS) ----
        float acc0 = 0.f, acc1 = 0.f;
#pragma unroll
        for (int j = 0; j < WPT; j += 4) {
            const int w = wbase + j;
            const uint4 hw4 = *(const uint4*)&hW[w];    // wave-uniform broadcast
            acc0 = fdot2u(ur[j + 0].x, hw4.x, acc0); acc1 = fdot2u(ur[j + 0].y, hw4.x, acc1);
            acc0 = fdot2u(ur[j + 1].x, hw4.y, acc0); acc1 = fdot2u(ur[j + 1].y, hw4.y, acc1);
            acc0 = fdot2u(ur[j + 2].x, hw4.z, acc0); acc1 = fdot2u(ur[j + 2].y, hw4.z, acc1);
            acc0 = fdot2u(ur[j + 3].x, hw4.w, acc0); acc1 = fdot2u(ur[j + 3].y, hw4.w, acc1);
        }
        *(float2*)&zpS[kq * COLSP + c0] = make_float2(acc0, acc1);
        bar_lds();          // bar1

        // ---- phase B: cell update (threads < 128), h stays in LDS (f16) ----
        if (tid < HN) {
            float zg[4];
#pragma unroll
            for (int g = 0; g < 4; ++g) {
                float zs = z4[g];
#pragma unroll
                for (int r = 0; r < NKG; ++r) zs += zpS[r * COLSP + g * HN + tid];
                zg[g] = zs;
            }
            if (t + 1 < T_) {   // prefetch next xz
#pragma unroll
                for (int g = 0; g < 4; ++g)
                    z4[g] = xzcell[(size_t)(t + 1) * GATES + g * HN];
            }
            const float ig = fsig(zg[0]);
            const float fg = fsig(zg[1]);
            const float gg = ftanh(zg[2]);
            const float og = fsig(zg[3]);
            cst = fg * cst + ig * gg;
            const float hnew = og * ftanh(cst);

            if (t == T_ - 1) {
                out_last[(size_t)b * HN + tid] = hnew;
            } else {
                reinterpret_cast<unsigned short*>(hW)[tid] = f2h_bits(hnew);
            }
        }
        bar_lds();          // bar2 -> next dot sees h(t+1)
    }
}

// ---------------------------------------------------------------------------
// Launch
// ---------------------------------------------------------------------------
extern "C" void kernel_launch(void* const* d_in, const int* in_sizes, int n_in,
                              void* d_out, int out_size, void* d_ws, size_t ws_size,
                              hipStream_t stream)
{
    const float* x  = (const float*)d_in[0];
    const float* W0 = (const float*)d_in[1];
    const float* U0 = (const float*)d_in[2];
    const float* b0 = (const float*)d_in[3];
    const float* W1 = (const float*)d_in[4];
    const float* U1 = (const float*)d_in[5];
    const float* b1 = (const float*)d_in[6];
    const float* W2 = (const float*)d_in[7];
    const float* U2 = (const float*)d_in[8];
    const float* b2 = (const float*)d_in[9];
    const float* m0 = (const float*)d_in[10];
    const float* m1 = (const float*)d_in[11];
    const float* m2 = (const float*)d_in[12];
    float* out = (float*)d_out;

    // workspace layout:
    //   xz    : 134217728 B   (64*512*1024 floats, reused by all 3 layers)
    //   h0    :  33554432 B
    //   h1    :  33554432 B
    //   hbuf  : 2 regions x 131072 B (2 x 64 x 256 tagged words per layer)
    char* ws = (char*)d_ws;
    float* xz = (float*)ws;
    float* h0 = (float*)(ws + 134217728);
    float* h1 = (float*)(ws + 134217728 + 33554432);
    unsigned int* hb0 = (unsigned int*)(ws + 134217728 + 2 * 33554432);
    unsigned int* hb1 = hb0 + 2 * B_ * 256;

    const int M = B_ * T_;  // 32768

    // Layer 0
    gemm_mask_mfma<<<dim3(1024 / 128, M / 128), 256, 0, stream>>>(x, W0, b0, m0, xz, M, 1024, 128);
    lstm_rec_v16<256, true><<<256, 1024, 0, stream>>>(xz, U0, h0, nullptr, hb0);

    // Layer 1
    gemm_mask_mfma<<<dim3(1024 / 128, M / 128), 256, 0, stream>>>(h0, W1, b1, m1, xz, M, 1024, 256);
    lstm_rec_v16<256, true><<<256, 1024, 0, stream>>>(xz, U1, h1, nullptr, hb1);

    // Layer 2 (H=128): one block per batch, NO exchange, f16 fdot2 dot
    gemm_mask_mfma<<<dim3(512 / 128, M / 128), 256, 0, stream>>>(h1, W2, b2, m2, xz, M, 512, 256);
    lstm_full_v18d<<<64, 1024, 0, stream>>>(xz, U2, out);
}